// Round 1
// baseline (905.096 us; speedup 1.0000x reference)
//
#include <hip/hip_runtime.h>
#include <hip/hip_bf16.h>

#define N_GRAPHS 64
#define TPAD 68   // padded LDS row stride (floats) to break bank alignment

// ---------------- CSR build ----------------

__global__ void hist_kernel(const int* __restrict__ dst, int* __restrict__ deg, int E) {
    int g = blockIdx.x * blockDim.x + threadIdx.x;
    if (g < E) atomicAdd(&deg[dst[g]], 1);
}

// single-block exclusive scan, wave-shfl based (3 barriers/chunk)
__global__ void scan_kernel(const int* __restrict__ in, int* __restrict__ out, int n) {
    __shared__ int wtot[16];
    __shared__ int carry_s;
    const int tid = threadIdx.x;
    const int lane = tid & 63;
    const int wid = tid >> 6;
    if (tid == 0) carry_s = 0;
    __syncthreads();
    for (int base = 0; base < n; base += 1024) {
        int idx = base + tid;
        int v = (idx < n) ? in[idx] : 0;
        int s = v;
        #pragma unroll
        for (int off = 1; off < 64; off <<= 1) {
            int t = __shfl_up(s, off);
            if (lane >= off) s += t;
        }
        if (lane == 63) wtot[wid] = s;
        __syncthreads();
        if (tid == 0) {
            int acc = carry_s;
            #pragma unroll
            for (int w = 0; w < 16; ++w) { int t = wtot[w]; wtot[w] = acc; acc += t; }
            carry_s = acc;
        }
        __syncthreads();
        if (idx < n) out[idx] = wtot[wid] + s - v;
        __syncthreads();
    }
    if (tid == 0) out[n] = carry_s;
}

__global__ void dis_cursor_kernel(const int* __restrict__ deg, const int* __restrict__ rs,
                                  float* __restrict__ dis, int* __restrict__ cur, int n) {
    int g = blockIdx.x * blockDim.x + threadIdx.x;
    if (g < n) {
        dis[g] = 1.0f / sqrtf((float)deg[g] + 1.0f);
        cur[g] = rs[g];
    }
}

__global__ void fill_kernel(const int* __restrict__ src, const int* __restrict__ dst,
                            int* __restrict__ cur, int* __restrict__ col, int E) {
    int g = blockIdx.x * blockDim.x + threadIdx.x;
    if (g < E) {
        int p = atomicAdd(&cur[dst[g]], 1);
        col[p] = src[g];
    }
}

// ---------------- transforms ----------------

// x [n,4] @ W1 [4,64] -> t [n,64]; thread per output element
__global__ void transform1_kernel(const float* __restrict__ x, const float* __restrict__ W1,
                                  float* __restrict__ t, int n) {
    int gid = blockIdx.x * blockDim.x + threadIdx.x;
    int i = gid >> 6, f = gid & 63;
    if (i >= n) return;
    float x0 = x[i * 4 + 0], x1 = x[i * 4 + 1], x2 = x[i * 4 + 2], x3 = x[i * 4 + 3];
    t[gid] = x0 * W1[f] + x1 * W1[64 + f] + x2 * W1[128 + f] + x3 * W1[192 + f];
}

// h [n,64] @ W [64,64] -> t [n,64]; 64-node tile, 4x4 register blocking
__global__ void transform64_kernel(const float* __restrict__ h, const float* __restrict__ W,
                                   float* __restrict__ t, int n) {
    __shared__ float Wt[64 * TPAD];   // Wt[f*TPAD+k]
    __shared__ float Hs[64 * TPAD];   // Hs[nn*TPAD+k]
    const int tid = threadIdx.x;
    const int base = blockIdx.x * 64;
    for (int idx = tid; idx < 4096; idx += 256) {
        int k = idx >> 6, f = idx & 63;
        Wt[f * TPAD + k] = W[idx];
    }
    for (int idx = tid; idx < 4096; idx += 256) {
        int nn = idx >> 6, k = idx & 63;
        int node = base + nn;
        Hs[nn * TPAD + k] = (node < n) ? h[node * 64 + k] : 0.0f;
    }
    __syncthreads();
    const int tf = tid & 15;   // feats tf*4 ..
    const int tn = tid >> 4;   // nodes tn*4 ..
    float acc[4][4] = {};
    for (int k = 0; k < 64; k += 4) {
        float4 w4[4], h4[4];
        #pragma unroll
        for (int ff = 0; ff < 4; ++ff) w4[ff] = *(const float4*)&Wt[(tf * 4 + ff) * TPAD + k];
        #pragma unroll
        for (int nn = 0; nn < 4; ++nn) h4[nn] = *(const float4*)&Hs[(tn * 4 + nn) * TPAD + k];
        #pragma unroll
        for (int nn = 0; nn < 4; ++nn)
            #pragma unroll
            for (int ff = 0; ff < 4; ++ff)
                acc[nn][ff] += h4[nn].x * w4[ff].x + h4[nn].y * w4[ff].y +
                               h4[nn].z * w4[ff].z + h4[nn].w * w4[ff].w;
    }
    #pragma unroll
    for (int nn = 0; nn < 4; ++nn) {
        int node = base + tn * 4 + nn;
        if (node < n) {
            float4 o = make_float4(acc[nn][0], acc[nn][1], acc[nn][2], acc[nn][3]);
            *(float4*)&t[node * 64 + tf * 4] = o;
        }
    }
}

// h [n,64] @ W3 [64,32] -> t [n,32]; 128-node tile
__global__ void transform64_32_kernel(const float* __restrict__ h, const float* __restrict__ W,
                                      float* __restrict__ t, int n) {
    __shared__ float Wt[32 * TPAD];    // Wt[f*TPAD+k]
    __shared__ float Hs[128 * TPAD];
    const int tid = threadIdx.x;
    const int base = blockIdx.x * 128;
    for (int idx = tid; idx < 2048; idx += 256) {
        int k = idx >> 5, f = idx & 31;
        Wt[f * TPAD + k] = W[idx];
    }
    for (int idx = tid; idx < 8192; idx += 256) {
        int nn = idx >> 6, k = idx & 63;
        int node = base + nn;
        Hs[nn * TPAD + k] = (node < n) ? h[node * 64 + k] : 0.0f;
    }
    __syncthreads();
    const int tf = tid & 7;    // feats tf*4 .. (32 total)
    const int tn = tid >> 3;   // nodes tn*4 .. (128 total)
    float acc[4][4] = {};
    for (int k = 0; k < 64; k += 4) {
        float4 w4[4], h4[4];
        #pragma unroll
        for (int ff = 0; ff < 4; ++ff) w4[ff] = *(const float4*)&Wt[(tf * 4 + ff) * TPAD + k];
        #pragma unroll
        for (int nn = 0; nn < 4; ++nn) h4[nn] = *(const float4*)&Hs[(tn * 4 + nn) * TPAD + k];
        #pragma unroll
        for (int nn = 0; nn < 4; ++nn)
            #pragma unroll
            for (int ff = 0; ff < 4; ++ff)
                acc[nn][ff] += h4[nn].x * w4[ff].x + h4[nn].y * w4[ff].y +
                               h4[nn].z * w4[ff].z + h4[nn].w * w4[ff].w;
    }
    #pragma unroll
    for (int nn = 0; nn < 4; ++nn) {
        int node = base + tn * 4 + nn;
        if (node < n) {
            float4 o = make_float4(acc[nn][0], acc[nn][1], acc[nn][2], acc[nn][3]);
            *(float4*)&t[node * 32 + tf * 4] = o;
        }
    }
}

// ---------------- aggregation (gather over CSR) ----------------

template <int F, bool RELU>
__global__ void aggregate_kernel(const float* __restrict__ t, const int* __restrict__ col,
                                 const int* __restrict__ rs, const float* __restrict__ dis,
                                 const float* __restrict__ b, float* __restrict__ out, int n) {
    int gid = blockIdx.x * blockDim.x + threadIdx.x;
    int i, f;
    if (F == 64) { i = gid >> 6; f = threadIdx.x & 63; }
    else         { i = gid >> 5; f = threadIdx.x & 31; }
    if (i >= n) return;
    float di = dis[i];
    float acc = 0.0f;
    int e = rs[i];
    const int end = rs[i + 1];
    for (; e + 4 <= end; e += 4) {
        int s0 = col[e], s1 = col[e + 1], s2 = col[e + 2], s3 = col[e + 3];
        float w0 = dis[s0], w1 = dis[s1], w2 = dis[s2], w3 = dis[s3];
        float v0 = t[s0 * F + f], v1 = t[s1 * F + f], v2 = t[s2 * F + f], v3 = t[s3 * F + f];
        acc += w0 * v0;
        acc += w1 * v1;
        acc += w2 * v2;
        acc += w3 * v3;
    }
    for (; e < end; ++e) {
        int s = col[e];
        acc += dis[s] * t[s * F + f];
    }
    float r = di * acc + di * di * t[i * F + f] + b[f];
    if (RELU) r = fmaxf(r, 0.0f);
    out[i * F + f] = r;
}

// ---------------- readout ----------------

__device__ __forceinline__ unsigned mapf(float v) {
    unsigned u = __float_as_uint(v);
    return u ^ ((u & 0x80000000u) ? 0xFFFFFFFFu : 0x80000000u);
}

#define MAPPED_NEG_INF 0x007FFFFFu

__global__ void init_readout_kernel(float* __restrict__ gsum, unsigned* __restrict__ gmax,
                                    int* __restrict__ gcnt) {
    int idx = blockIdx.x * blockDim.x + threadIdx.x;
    if (idx < N_GRAPHS * 32) { gsum[idx] = 0.0f; gmax[idx] = MAPPED_NEG_INF; }
    if (idx < N_GRAPHS) gcnt[idx] = 0;
}

#define R_CHUNK 512
__global__ void readout_kernel(const float* __restrict__ emb, const int* __restrict__ batch,
                               float* __restrict__ gsum, unsigned* __restrict__ gmax,
                               int* __restrict__ gcnt, int n) {
    __shared__ float ssum[N_GRAPHS * 32];
    __shared__ unsigned smax[N_GRAPHS * 32];
    __shared__ int scnt[N_GRAPHS];
    const int tid = threadIdx.x;
    for (int idx = tid; idx < N_GRAPHS * 32; idx += 256) { ssum[idx] = 0.0f; smax[idx] = MAPPED_NEG_INF; }
    if (tid < N_GRAPHS) scnt[tid] = 0;
    __syncthreads();
    const int lane = tid & 31, grp = tid >> 5;   // 8 groups of 32
    const int start = blockIdx.x * R_CHUNK;
    const int end = min(start + R_CHUNK, n);
    for (int i = start + grp; i < end; i += 8) {
        int g = batch[i];
        float v = emb[i * 32 + lane];
        atomicAdd(&ssum[g * 32 + lane], v);
        atomicMax(&smax[g * 32 + lane], mapf(v));
        if (lane == 0) atomicAdd(&scnt[g], 1);
    }
    __syncthreads();
    for (int idx = tid; idx < N_GRAPHS * 32; idx += 256) {
        int g = idx >> 5;
        if (scnt[g] > 0) {
            atomicAdd(&gsum[idx], ssum[idx]);
            atomicMax(&gmax[idx], smax[idx]);
        }
    }
    if (tid < N_GRAPHS && scnt[tid] > 0) atomicAdd(&gcnt[tid], scnt[tid]);
}

__global__ void finalize_kernel(const float* __restrict__ gsum, const unsigned* __restrict__ gmax,
                                const int* __restrict__ gcnt, float* __restrict__ out) {
    int idx = blockIdx.x * blockDim.x + threadIdx.x;
    if (idx >= N_GRAPHS * 32) return;
    int g = idx >> 5, f = idx & 31;
    float c = fmaxf((float)gcnt[g], 1.0f);
    out[g * 64 + f] = gsum[idx] / c;
    unsigned u = gmax[idx];
    unsigned bits = (u & 0x80000000u) ? (u ^ 0x80000000u) : ~u;
    out[g * 64 + 32 + f] = __uint_as_float(bits);
}

// ---------------- launch ----------------

extern "C" void kernel_launch(void* const* d_in, const int* in_sizes, int n_in,
                              void* d_out, int out_size, void* d_ws, size_t ws_size,
                              hipStream_t stream) {
    const float* x  = (const float*)d_in[0];
    const float* W1 = (const float*)d_in[1];
    const float* b1 = (const float*)d_in[2];
    const float* W2 = (const float*)d_in[3];
    const float* b2 = (const float*)d_in[4];
    const float* W3 = (const float*)d_in[5];
    const float* b3 = (const float*)d_in[6];
    const int* edge_index = (const int*)d_in[7];
    const int* batch = (const int*)d_in[8];
    float* out = (float*)d_out;

    const int N = in_sizes[0] / 4;
    const int E = in_sizes[7] / 2;
    const int* src = edge_index;
    const int* dst = edge_index + E;

    // workspace carve-up (256B aligned)
    char* p = (char*)d_ws;
    auto alloc = [&](size_t bytes) { void* r = (void*)p; p += (bytes + 255) & ~(size_t)255; return r; };
    int*      deg  = (int*)alloc((size_t)N * 4);
    int*      rs   = (int*)alloc((size_t)(N + 1) * 4);
    int*      cur  = (int*)alloc((size_t)N * 4);
    float*    dis  = (float*)alloc((size_t)N * 4);
    int*      col  = (int*)alloc((size_t)E * 4);
    float*    T    = (float*)alloc((size_t)N * 64 * 4);
    float*    H    = (float*)alloc((size_t)N * 64 * 4);
    float*    gsum = (float*)alloc((size_t)N_GRAPHS * 32 * 4);
    unsigned* gmax = (unsigned*)alloc((size_t)N_GRAPHS * 32 * 4);
    int*      gcnt = (int*)alloc((size_t)N_GRAPHS * 4);
    (void)ws_size; (void)n_in; (void)out_size;

    const int gE = (E + 255) / 256;
    const int gN = (N + 255) / 256;

    // CSR build
    hipMemsetAsync(deg, 0, (size_t)N * 4, stream);
    hist_kernel<<<gE, 256, 0, stream>>>(dst, deg, E);
    scan_kernel<<<1, 1024, 0, stream>>>(deg, rs, N);
    dis_cursor_kernel<<<gN, 256, 0, stream>>>(deg, rs, dis, cur, N);
    fill_kernel<<<gE, 256, 0, stream>>>(src, dst, cur, col, E);

    // layer 1
    transform1_kernel<<<(N * 64 + 255) / 256, 256, 0, stream>>>(x, W1, T, N);
    aggregate_kernel<64, true><<<(N * 64 + 255) / 256, 256, 0, stream>>>(T, col, rs, dis, b1, H, N);
    // layer 2
    transform64_kernel<<<(N + 63) / 64, 256, 0, stream>>>(H, W2, T, N);
    aggregate_kernel<64, true><<<(N * 64 + 255) / 256, 256, 0, stream>>>(T, col, rs, dis, b2, H, N);
    // layer 3
    transform64_32_kernel<<<(N + 127) / 128, 256, 0, stream>>>(H, W3, T, N);
    aggregate_kernel<32, false><<<(N * 32 + 255) / 256, 256, 0, stream>>>(T, col, rs, dis, b3, H, N);

    // readout
    init_readout_kernel<<<(N_GRAPHS * 32 + 255) / 256, 256, 0, stream>>>(gsum, gmax, gcnt);
    readout_kernel<<<(N + R_CHUNK - 1) / R_CHUNK, 256, 0, stream>>>(H, batch, gsum, gmax, gcnt, N);
    finalize_kernel<<<(N_GRAPHS * 32 + 255) / 256, 256, 0, stream>>>(gsum, gmax, gcnt, out);
}

// Round 2
// 602.469 us; speedup vs baseline: 1.5023x; 1.5023x over previous
//
#include <hip/hip_runtime.h>
#include <hip/hip_bf16.h>

#define N_GRAPHS 64
#define TPAD 68   // padded LDS row stride (floats)

// ---------------- degree histogram ----------------

__global__ void hist_kernel(const int* __restrict__ dst, int* __restrict__ deg, int E) {
    int g = blockIdx.x * blockDim.x + threadIdx.x;
    if (g < E) atomicAdd(&deg[dst[g]], 1);
}

// ---------------- multi-block exclusive scan of deg -> rs ----------------
// chunk = 1024 elements per block (256 threads x int4)

__global__ void scan_partial_kernel(const int* __restrict__ deg, int* __restrict__ part, int n) {
    __shared__ int ws[4];
    const int tid = threadIdx.x;
    int idx = blockIdx.x * 1024 + tid * 4;
    int4 v = make_int4(0, 0, 0, 0);
    if (idx + 3 < n) v = *(const int4*)&deg[idx];
    else {
        if (idx + 0 < n) v.x = deg[idx + 0];
        if (idx + 1 < n) v.y = deg[idx + 1];
        if (idx + 2 < n) v.z = deg[idx + 2];
        if (idx + 3 < n) v.w = deg[idx + 3];
    }
    int s = v.x + v.y + v.z + v.w;
    #pragma unroll
    for (int off = 1; off < 64; off <<= 1) s += __shfl_xor(s, off);
    if ((tid & 63) == 0) ws[tid >> 6] = s;
    __syncthreads();
    if (tid == 0) part[blockIdx.x] = ws[0] + ws[1] + ws[2] + ws[3];
}

// exclusive scan of partials (nparts <= 128), also writes rs[n] = total
__global__ void scan_offsets_kernel(int* __restrict__ part, int nparts, int* __restrict__ rs, int n) {
    __shared__ int sh[128];
    const int tid = threadIdx.x;
    int v = (tid < nparts) ? part[tid] : 0;
    sh[tid] = v;
    __syncthreads();
    for (int off = 1; off < 128; off <<= 1) {
        int t = (tid >= off) ? sh[tid - off] : 0;
        __syncthreads();
        sh[tid] += t;
        __syncthreads();
    }
    if (tid < nparts) part[tid] = sh[tid] - v;
    if (tid == nparts - 1) rs[n] = sh[tid];
}

__global__ void scan_final_kernel(const int* __restrict__ deg, const int* __restrict__ part,
                                  int* __restrict__ rs, int n) {
    __shared__ int wsum[4];
    const int tid = threadIdx.x;
    const int lane = tid & 63, wid = tid >> 6;
    int idx = blockIdx.x * 1024 + tid * 4;
    int4 v = make_int4(0, 0, 0, 0);
    if (idx + 3 < n) v = *(const int4*)&deg[idx];
    else {
        if (idx + 0 < n) v.x = deg[idx + 0];
        if (idx + 1 < n) v.y = deg[idx + 1];
        if (idx + 2 < n) v.z = deg[idx + 2];
        if (idx + 3 < n) v.w = deg[idx + 3];
    }
    const int tsum = v.x + v.y + v.z + v.w;
    int s = tsum;
    #pragma unroll
    for (int off = 1; off < 64; off <<= 1) {
        int t = __shfl_up(s, off);
        if (lane >= off) s += t;
    }
    if (lane == 63) wsum[wid] = s;
    __syncthreads();
    int woff = part[blockIdx.x];
    for (int w = 0; w < wid; ++w) woff += wsum[w];
    const int excl = woff + s - tsum;
    if (idx < n)     rs[idx]     = excl;
    if (idx + 1 < n) rs[idx + 1] = excl + v.x;
    if (idx + 2 < n) rs[idx + 2] = excl + v.x + v.y;
    if (idx + 3 < n) rs[idx + 3] = excl + v.x + v.y + v.z;
}

// ---------------- dis + bucket cursors ----------------

__global__ void dis_bcur_kernel(const int* __restrict__ deg, const int* __restrict__ rs,
                                float* __restrict__ dis, int* __restrict__ bcur,
                                int n, int nbuck) {
    int g = blockIdx.x * blockDim.x + threadIdx.x;
    if (g < n) dis[g] = rsqrtf((float)deg[g] + 1.0f);
    if (g < nbuck) bcur[g] = rs[g << 8];
}

// ---------------- binned CSR build ----------------
// bucket = dst >> 8 (256 nodes per bucket). packed edge = (dst&255)<<24 | src

#define EBC 4096
__global__ void binscatter_kernel(const int* __restrict__ src, const int* __restrict__ dst,
                                  int* __restrict__ bcur, unsigned* __restrict__ binned,
                                  int E, int nbuck) {
    __shared__ int lhist[512];
    __shared__ int lbase[512];
    const int tid = threadIdx.x;
    const int e0 = blockIdx.x * EBC;
    const int e1 = min(e0 + EBC, E);
    for (int i = tid; i < nbuck; i += 256) lhist[i] = 0;
    __syncthreads();
    for (int e = e0 + tid; e < e1; e += 256) atomicAdd(&lhist[((unsigned)dst[e]) >> 8], 1);
    __syncthreads();
    for (int i = tid; i < nbuck; i += 256) {
        int c = lhist[i];
        lbase[i] = (c > 0) ? atomicAdd(&bcur[i], c) : 0;
        lhist[i] = 0;
    }
    __syncthreads();
    for (int e = e0 + tid; e < e1; e += 256) {
        int d = dst[e];
        int b = ((unsigned)d) >> 8;
        int off = atomicAdd(&lhist[b], 1);
        binned[lbase[b] + off] = ((unsigned)(d & 255) << 24) | (unsigned)src[e];
    }
}

__global__ void bucketsort_kernel(const unsigned* __restrict__ binned, const int* __restrict__ rs,
                                  int* __restrict__ col, int n) {
    __shared__ int lcur[256];
    const int node_base = blockIdx.x << 8;
    const int nb = min(256, n - node_base);
    const int tid = threadIdx.x;
    if (tid < nb) lcur[tid] = rs[node_base + tid];
    __syncthreads();
    const int e0 = rs[node_base];
    const int e1 = rs[node_base + nb];
    for (int e = e0 + tid; e < e1; e += 256) {
        unsigned v = binned[e];
        int p = atomicAdd(&lcur[v >> 24], 1);
        col[p] = (int)(v & 0xFFFFFFu);
    }
}

// ---------------- transforms (output pre-scaled by dis[i]) ----------------

__global__ void transform1_kernel(const float* __restrict__ x, const float* __restrict__ W1,
                                  const float* __restrict__ dis, float* __restrict__ t, int n) {
    int gid = blockIdx.x * blockDim.x + threadIdx.x;
    int i = gid >> 6, f = gid & 63;
    if (i >= n) return;
    float4 xv = *(const float4*)&x[i * 4];
    t[gid] = dis[i] * (xv.x * W1[f] + xv.y * W1[64 + f] + xv.z * W1[128 + f] + xv.w * W1[192 + f]);
}

__global__ void transform64_kernel(const float* __restrict__ h, const float* __restrict__ W,
                                   const float* __restrict__ dis, float* __restrict__ t, int n) {
    __shared__ float Wt[64 * TPAD];
    __shared__ float Hs[64 * TPAD];
    const int tid = threadIdx.x;
    const int base = blockIdx.x * 64;
    for (int idx = tid; idx < 4096; idx += 256) {
        int k = idx >> 6, f = idx & 63;
        Wt[f * TPAD + k] = W[idx];
    }
    for (int idx = tid; idx < 4096; idx += 256) {
        int nn = idx >> 6, k = idx & 63;
        int node = base + nn;
        Hs[nn * TPAD + k] = (node < n) ? h[node * 64 + k] : 0.0f;
    }
    __syncthreads();
    const int tf = tid & 15;
    const int tn = tid >> 4;
    float acc[4][4] = {};
    for (int k = 0; k < 64; k += 4) {
        float4 w4[4], h4[4];
        #pragma unroll
        for (int ff = 0; ff < 4; ++ff) w4[ff] = *(const float4*)&Wt[(tf * 4 + ff) * TPAD + k];
        #pragma unroll
        for (int nn = 0; nn < 4; ++nn) h4[nn] = *(const float4*)&Hs[(tn * 4 + nn) * TPAD + k];
        #pragma unroll
        for (int nn = 0; nn < 4; ++nn)
            #pragma unroll
            for (int ff = 0; ff < 4; ++ff)
                acc[nn][ff] += h4[nn].x * w4[ff].x + h4[nn].y * w4[ff].y +
                               h4[nn].z * w4[ff].z + h4[nn].w * w4[ff].w;
    }
    #pragma unroll
    for (int nn = 0; nn < 4; ++nn) {
        int node = base + tn * 4 + nn;
        if (node < n) {
            float d = dis[node];
            float4 o = make_float4(d * acc[nn][0], d * acc[nn][1], d * acc[nn][2], d * acc[nn][3]);
            *(float4*)&t[node * 64 + tf * 4] = o;
        }
    }
}

__global__ void transform64_32_kernel(const float* __restrict__ h, const float* __restrict__ W,
                                      const float* __restrict__ dis, float* __restrict__ t, int n) {
    __shared__ float Wt[32 * TPAD];
    __shared__ float Hs[128 * TPAD];
    const int tid = threadIdx.x;
    const int base = blockIdx.x * 128;
    for (int idx = tid; idx < 2048; idx += 256) {
        int k = idx >> 5, f = idx & 31;
        Wt[f * TPAD + k] = W[idx];
    }
    for (int idx = tid; idx < 8192; idx += 256) {
        int nn = idx >> 6, k = idx & 63;
        int node = base + nn;
        Hs[nn * TPAD + k] = (node < n) ? h[node * 64 + k] : 0.0f;
    }
    __syncthreads();
    const int tf = tid & 7;
    const int tn = tid >> 3;
    float acc[4][4] = {};
    for (int k = 0; k < 64; k += 4) {
        float4 w4[4], h4[4];
        #pragma unroll
        for (int ff = 0; ff < 4; ++ff) w4[ff] = *(const float4*)&Wt[(tf * 4 + ff) * TPAD + k];
        #pragma unroll
        for (int nn = 0; nn < 4; ++nn) h4[nn] = *(const float4*)&Hs[(tn * 4 + nn) * TPAD + k];
        #pragma unroll
        for (int nn = 0; nn < 4; ++nn)
            #pragma unroll
            for (int ff = 0; ff < 4; ++ff)
                acc[nn][ff] += h4[nn].x * w4[ff].x + h4[nn].y * w4[ff].y +
                               h4[nn].z * w4[ff].z + h4[nn].w * w4[ff].w;
    }
    #pragma unroll
    for (int nn = 0; nn < 4; ++nn) {
        int node = base + tn * 4 + nn;
        if (node < n) {
            float d = dis[node];
            float4 o = make_float4(d * acc[nn][0], d * acc[nn][1], d * acc[nn][2], d * acc[nn][3]);
            *(float4*)&t[node * 32 + tf * 4] = o;
        }
    }
}

// ---------------- aggregation (gather over CSR, T pre-scaled by dis) ----------------

template <int F, bool RELU>
__global__ void aggregate_kernel(const float* __restrict__ t, const int* __restrict__ col,
                                 const int* __restrict__ rs, const float* __restrict__ dis,
                                 const float* __restrict__ b, float* __restrict__ out, int n) {
    int gid = blockIdx.x * blockDim.x + threadIdx.x;
    int i, f;
    if (F == 64) { i = gid >> 6; f = threadIdx.x & 63; }
    else         { i = gid >> 5; f = threadIdx.x & 31; }
    if (i >= n) return;
    float acc0 = 0.0f, acc1 = 0.0f;
    int e = rs[i];
    const int end = rs[i + 1];
    for (; e + 8 <= end; e += 8) {
        int s0 = col[e],     s1 = col[e + 1], s2 = col[e + 2], s3 = col[e + 3];
        int s4 = col[e + 4], s5 = col[e + 5], s6 = col[e + 6], s7 = col[e + 7];
        float v0 = t[s0 * F + f], v1 = t[s1 * F + f], v2 = t[s2 * F + f], v3 = t[s3 * F + f];
        float v4 = t[s4 * F + f], v5 = t[s5 * F + f], v6 = t[s6 * F + f], v7 = t[s7 * F + f];
        acc0 += v0; acc1 += v1; acc0 += v2; acc1 += v3;
        acc0 += v4; acc1 += v5; acc0 += v6; acc1 += v7;
    }
    for (; e < end; ++e) acc0 += t[col[e] * F + f];
    float r = dis[i] * (acc0 + acc1 + t[i * F + f]) + b[f];
    if (RELU) r = fmaxf(r, 0.0f);
    out[i * F + f] = r;
}

// ---------------- readout ----------------

__device__ __forceinline__ unsigned mapf(float v) {
    unsigned u = __float_as_uint(v);
    return u ^ ((u & 0x80000000u) ? 0xFFFFFFFFu : 0x80000000u);
}

#define MAPPED_NEG_INF 0x007FFFFFu

__global__ void init_readout_kernel(float* __restrict__ gsum, unsigned* __restrict__ gmax,
                                    int* __restrict__ gcnt) {
    int idx = blockIdx.x * blockDim.x + threadIdx.x;
    if (idx < N_GRAPHS * 32) { gsum[idx] = 0.0f; gmax[idx] = MAPPED_NEG_INF; }
    if (idx < N_GRAPHS) gcnt[idx] = 0;
}

#define R_CHUNK 512
__global__ void readout_kernel(const float* __restrict__ emb, const int* __restrict__ batch,
                               float* __restrict__ gsum, unsigned* __restrict__ gmax,
                               int* __restrict__ gcnt, int n) {
    __shared__ float ssum[N_GRAPHS * 32];
    __shared__ unsigned smax[N_GRAPHS * 32];
    __shared__ int scnt[N_GRAPHS];
    const int tid = threadIdx.x;
    for (int idx = tid; idx < N_GRAPHS * 32; idx += 256) { ssum[idx] = 0.0f; smax[idx] = MAPPED_NEG_INF; }
    if (tid < N_GRAPHS) scnt[tid] = 0;
    __syncthreads();
    const int lane = tid & 31, grp = tid >> 5;
    const int start = blockIdx.x * R_CHUNK;
    const int end = min(start + R_CHUNK, n);
    for (int i = start + grp; i < end; i += 8) {
        int g = batch[i];
        float v = emb[i * 32 + lane];
        atomicAdd(&ssum[g * 32 + lane], v);
        atomicMax(&smax[g * 32 + lane], mapf(v));
        if (lane == 0) atomicAdd(&scnt[g], 1);
    }
    __syncthreads();
    for (int idx = tid; idx < N_GRAPHS * 32; idx += 256) {
        int g = idx >> 5;
        if (scnt[g] > 0) {
            atomicAdd(&gsum[idx], ssum[idx]);
            atomicMax(&gmax[idx], smax[idx]);
        }
    }
    if (tid < N_GRAPHS && scnt[tid] > 0) atomicAdd(&gcnt[tid], scnt[tid]);
}

__global__ void finalize_kernel(const float* __restrict__ gsum, const unsigned* __restrict__ gmax,
                                const int* __restrict__ gcnt, float* __restrict__ out) {
    int idx = blockIdx.x * blockDim.x + threadIdx.x;
    if (idx >= N_GRAPHS * 32) return;
    int g = idx >> 5, f = idx & 31;
    float c = fmaxf((float)gcnt[g], 1.0f);
    out[g * 64 + f] = gsum[idx] / c;
    unsigned u = gmax[idx];
    unsigned bits = (u & 0x80000000u) ? (u ^ 0x80000000u) : ~u;
    out[g * 64 + 32 + f] = __uint_as_float(bits);
}

// ---------------- launch ----------------

extern "C" void kernel_launch(void* const* d_in, const int* in_sizes, int n_in,
                              void* d_out, int out_size, void* d_ws, size_t ws_size,
                              hipStream_t stream) {
    const float* x  = (const float*)d_in[0];
    const float* W1 = (const float*)d_in[1];
    const float* b1 = (const float*)d_in[2];
    const float* W2 = (const float*)d_in[3];
    const float* b2 = (const float*)d_in[4];
    const float* W3 = (const float*)d_in[5];
    const float* b3 = (const float*)d_in[6];
    const int* edge_index = (const int*)d_in[7];
    const int* batch = (const int*)d_in[8];
    float* out = (float*)d_out;

    const int N = in_sizes[0] / 4;
    const int E = in_sizes[7] / 2;
    const int* src = edge_index;
    const int* dst = edge_index + E;
    const int nbuck = (N + 255) >> 8;           // <= 512
    const int nchunks = (N + 1023) / 1024;      // <= 128

    // workspace carve-up (256B aligned)
    char* p = (char*)d_ws;
    auto alloc = [&](size_t bytes) { void* r = (void*)p; p += (bytes + 255) & ~(size_t)255; return r; };
    int*      deg  = (int*)alloc((size_t)N * 4);
    int*      rs   = (int*)alloc((size_t)(N + 1) * 4);
    int*      part = (int*)alloc((size_t)128 * 4);
    int*      bcur = (int*)alloc((size_t)512 * 4);
    float*    dis  = (float*)alloc((size_t)N * 4);
    int*      col  = (int*)alloc((size_t)E * 4);
    float*    T    = (float*)alloc((size_t)N * 64 * 4);
    float*    H    = (float*)alloc((size_t)N * 64 * 4);
    float*    gsum = (float*)alloc((size_t)N_GRAPHS * 32 * 4);
    unsigned* gmax = (unsigned*)alloc((size_t)N_GRAPHS * 32 * 4);
    int*      gcnt = (int*)alloc((size_t)N_GRAPHS * 4);
    unsigned* binned = (unsigned*)T;   // aliased: consumed before T is written
    (void)ws_size; (void)n_in; (void)out_size;

    const int gE = (E + 255) / 256;
    const int gN = (N + 255) / 256;

    // CSR build (binned two-level sort)
    hipMemsetAsync(deg, 0, (size_t)N * 4, stream);
    hist_kernel<<<gE, 256, 0, stream>>>(dst, deg, E);
    scan_partial_kernel<<<nchunks, 256, 0, stream>>>(deg, part, N);
    scan_offsets_kernel<<<1, 128, 0, stream>>>(part, nchunks, rs, N);
    scan_final_kernel<<<nchunks, 256, 0, stream>>>(deg, part, rs, N);
    dis_bcur_kernel<<<gN, 256, 0, stream>>>(deg, rs, dis, bcur, N, nbuck);
    binscatter_kernel<<<(E + EBC - 1) / EBC, 256, 0, stream>>>(src, dst, bcur, binned, E, nbuck);
    bucketsort_kernel<<<nbuck, 256, 0, stream>>>(binned, rs, col, N);

    // layer 1
    transform1_kernel<<<(N * 64 + 255) / 256, 256, 0, stream>>>(x, W1, dis, T, N);
    aggregate_kernel<64, true><<<(N * 64 + 255) / 256, 256, 0, stream>>>(T, col, rs, dis, b1, H, N);
    // layer 2
    transform64_kernel<<<(N + 63) / 64, 256, 0, stream>>>(H, W2, dis, T, N);
    aggregate_kernel<64, true><<<(N * 64 + 255) / 256, 256, 0, stream>>>(T, col, rs, dis, b2, H, N);
    // layer 3
    transform64_32_kernel<<<(N + 127) / 128, 256, 0, stream>>>(H, W3, dis, T, N);
    aggregate_kernel<32, false><<<(N * 32 + 255) / 256, 256, 0, stream>>>(T, col, rs, dis, b3, H, N);

    // readout
    init_readout_kernel<<<(N_GRAPHS * 32 + 255) / 256, 256, 0, stream>>>(gsum, gmax, gcnt);
    readout_kernel<<<(N + R_CHUNK - 1) / R_CHUNK, 256, 0, stream>>>(H, batch, gsum, gmax, gcnt, N);
    finalize_kernel<<<(N_GRAPHS * 32 + 255) / 256, 256, 0, stream>>>(gsum, gmax, gcnt, out);
}

// Round 4
// 402.014 us; speedup vs baseline: 2.2514x; 1.4986x over previous
//
#include <hip/hip_runtime.h>
#include <hip/hip_bf16.h>

#define N_GRAPHS 64
#define TPAD 68   // padded LDS row stride (floats)

// ---------------- bucket-level histogram (bucket = dst>>8) ----------------

#define EBH 8192
__global__ void bucket_hist_kernel(const int* __restrict__ dst, int* __restrict__ bcnt,
                                   int E, int nbuck) {
    __shared__ int lh[512];
    const int tid = threadIdx.x;
    for (int i = tid; i < nbuck; i += 256) lh[i] = 0;
    __syncthreads();
    const int e0 = blockIdx.x * EBH;
    const int e1 = min(e0 + EBH, E);
    for (int e = e0 + tid; e < e1; e += 256)
        atomicAdd(&lh[((unsigned)dst[e]) >> 8], 1);
    __syncthreads();
    for (int i = tid; i < nbuck; i += 256) {
        int c = lh[i];
        if (c) atomicAdd(&bcnt[i], c);
    }
}

// exclusive scan of bucket counts (nbuck <= 512), seed bucket cursors
__global__ void bucket_scan_kernel(const int* __restrict__ bcnt, int* __restrict__ bbase,
                                   int* __restrict__ bcur, int nbuck) {
    __shared__ int sh[512];
    const int tid = threadIdx.x;
    int v = (tid < nbuck) ? bcnt[tid] : 0;
    sh[tid] = v;
    __syncthreads();
    for (int off = 1; off < 512; off <<= 1) {
        int t = (tid >= off) ? sh[tid - off] : 0;
        __syncthreads();
        sh[tid] += t;
        __syncthreads();
    }
    if (tid < nbuck) { int e = sh[tid] - v; bbase[tid] = e; bcur[tid] = e; }
    if (tid == nbuck - 1) bbase[nbuck] = sh[tid];
}

// ---------------- binned scatter: packed edge = (dst&255)<<24 | src ----------------

#define EBC 4096
__global__ void binscatter_kernel(const int* __restrict__ src, const int* __restrict__ dst,
                                  int* __restrict__ bcur, unsigned* __restrict__ binned,
                                  int E, int nbuck) {
    __shared__ int lhist[512];
    __shared__ int lbase[512];
    const int tid = threadIdx.x;
    const int e0 = blockIdx.x * EBC;
    const int e1 = min(e0 + EBC, E);
    for (int i = tid; i < nbuck; i += 256) lhist[i] = 0;
    __syncthreads();
    for (int e = e0 + tid; e < e1; e += 256) atomicAdd(&lhist[((unsigned)dst[e]) >> 8], 1);
    __syncthreads();
    for (int i = tid; i < nbuck; i += 256) {
        int c = lhist[i];
        lbase[i] = (c > 0) ? atomicAdd(&bcur[i], c) : 0;
        lhist[i] = 0;
    }
    __syncthreads();
    for (int e = e0 + tid; e < e1; e += 256) {
        int d = dst[e];
        int b = ((unsigned)d) >> 8;
        int off = atomicAdd(&lhist[b], 1);
        binned[lbase[b] + off] = ((unsigned)(d & 255) << 24) | (unsigned)src[e];
    }
}

// ---------------- per-bucket: node degrees, rs, dis, Xs=dis*x, CSR scatter ----------------

__global__ void build_bucket_kernel(const unsigned* __restrict__ binned, const int* __restrict__ bbase,
                                    const float* __restrict__ x, int* __restrict__ rs,
                                    float* __restrict__ dis_g, float* __restrict__ Xs,
                                    int* __restrict__ col, int n) {
    __shared__ int cnt[256];
    __shared__ int lcur[256];
    __shared__ int wsum[4];
    const int b = blockIdx.x;
    const int node_base = b << 8;
    const int nb = min(256, n - node_base);
    const int tid = threadIdx.x;
    cnt[tid] = 0;
    __syncthreads();
    const int e0 = bbase[b], e1 = bbase[b + 1];
    for (int e = e0 + tid; e < e1; e += 256)
        atomicAdd(&cnt[binned[e] >> 24], 1);
    __syncthreads();
    const int deg = cnt[tid];
    // exclusive scan over 256 entries
    const int lane = tid & 63, wid = tid >> 6;
    int s = deg;
    #pragma unroll
    for (int off = 1; off < 64; off <<= 1) {
        int t = __shfl_up(s, off);
        if (lane >= off) s += t;
    }
    if (lane == 63) wsum[wid] = s;
    __syncthreads();
    int woff = 0;
    for (int w = 0; w < wid; ++w) woff += wsum[w];
    const int excl = woff + s - deg;
    if (tid < nb) {
        int node = node_base + tid;
        rs[node] = e0 + excl;
        float d = rsqrtf((float)deg + 1.0f);
        dis_g[node] = d;
        float4 xv = *(const float4*)&x[node * 4];
        *(float4*)&Xs[node * 4] = make_float4(d * xv.x, d * xv.y, d * xv.z, d * xv.w);
    }
    lcur[tid] = e0 + excl;
    if (tid == 0 && node_base + nb == n) rs[n] = e1;
    __syncthreads();
    for (int e = e0 + tid; e < e1; e += 256) {
        unsigned v = binned[e];
        int p = atomicAdd(&lcur[v >> 24], 1);
        col[p] = (int)(v & 0xFFFFFFu);
    }
}

// ---------------- layer 1: aggregate x (4-dim) then transform ----------------

__global__ void agg4_kernel(const float* __restrict__ Xs, const int* __restrict__ col,
                            const int* __restrict__ rs, const float* __restrict__ dis,
                            float* __restrict__ aggX, int n) {
    int i = blockIdx.x * blockDim.x + threadIdx.x;
    if (i >= n) return;
    int e = rs[i];
    const int end = rs[i + 1];
    float4 a0 = make_float4(0, 0, 0, 0), a1 = make_float4(0, 0, 0, 0);
    for (; e + 2 <= end; e += 2) {
        int s0 = col[e], s1 = col[e + 1];
        float4 v0 = *(const float4*)&Xs[s0 * 4];
        float4 v1 = *(const float4*)&Xs[s1 * 4];
        a0.x += v0.x; a0.y += v0.y; a0.z += v0.z; a0.w += v0.w;
        a1.x += v1.x; a1.y += v1.y; a1.z += v1.z; a1.w += v1.w;
    }
    if (e < end) {
        float4 v = *(const float4*)&Xs[col[e] * 4];
        a0.x += v.x; a0.y += v.y; a0.z += v.z; a0.w += v.w;
    }
    float4 self = *(const float4*)&Xs[i * 4];
    float d = dis[i];
    float4 r = make_float4(d * (a0.x + a1.x + self.x), d * (a0.y + a1.y + self.y),
                           d * (a0.z + a1.z + self.z), d * (a0.w + a1.w + self.w));
    *(float4*)&aggX[i * 4] = r;
}

__global__ void transform1b_kernel(const float* __restrict__ aggX, const float* __restrict__ W1,
                                   const float* __restrict__ b1, float* __restrict__ H, int n) {
    int gid = blockIdx.x * blockDim.x + threadIdx.x;
    int i = gid >> 6, f = gid & 63;
    if (i >= n) return;
    float4 a = *(const float4*)&aggX[i * 4];
    float r = a.x * W1[f] + a.y * W1[64 + f] + a.z * W1[128 + f] + a.w * W1[192 + f] + b1[f];
    H[gid] = fmaxf(r, 0.0f);
}

// ---------------- transforms (output pre-scaled by dis[i]) ----------------

__global__ void transform64_kernel(const float* __restrict__ h, const float* __restrict__ W,
                                   const float* __restrict__ dis, float* __restrict__ t, int n) {
    __shared__ float Wt[64 * TPAD];
    __shared__ float Hs[64 * TPAD];
    const int tid = threadIdx.x;
    const int base = blockIdx.x * 64;
    for (int idx = tid; idx < 4096; idx += 256) {
        int k = idx >> 6, f = idx & 63;
        Wt[f * TPAD + k] = W[idx];
    }
    for (int idx = tid; idx < 4096; idx += 256) {
        int nn = idx >> 6, k = idx & 63;
        int node = base + nn;
        Hs[nn * TPAD + k] = (node < n) ? h[node * 64 + k] : 0.0f;
    }
    __syncthreads();
    const int tf = tid & 15;
    const int tn = tid >> 4;
    float acc[4][4] = {};
    for (int k = 0; k < 64; k += 4) {
        float4 w4[4], h4[4];
        #pragma unroll
        for (int ff = 0; ff < 4; ++ff) w4[ff] = *(const float4*)&Wt[(tf * 4 + ff) * TPAD + k];
        #pragma unroll
        for (int nn = 0; nn < 4; ++nn) h4[nn] = *(const float4*)&Hs[(tn * 4 + nn) * TPAD + k];
        #pragma unroll
        for (int nn = 0; nn < 4; ++nn)
            #pragma unroll
            for (int ff = 0; ff < 4; ++ff)
                acc[nn][ff] += h4[nn].x * w4[ff].x + h4[nn].y * w4[ff].y +
                               h4[nn].z * w4[ff].z + h4[nn].w * w4[ff].w;
    }
    #pragma unroll
    for (int nn = 0; nn < 4; ++nn) {
        int node = base + tn * 4 + nn;
        if (node < n) {
            float d = dis[node];
            float4 o = make_float4(d * acc[nn][0], d * acc[nn][1], d * acc[nn][2], d * acc[nn][3]);
            *(float4*)&t[node * 64 + tf * 4] = o;
        }
    }
}

__global__ void transform64_32_kernel(const float* __restrict__ h, const float* __restrict__ W,
                                      const float* __restrict__ dis, float* __restrict__ t, int n) {
    __shared__ float Wt[32 * TPAD];
    __shared__ float Hs[128 * TPAD];
    const int tid = threadIdx.x;
    const int base = blockIdx.x * 128;
    for (int idx = tid; idx < 2048; idx += 256) {
        int k = idx >> 5, f = idx & 31;
        Wt[f * TPAD + k] = W[idx];
    }
    for (int idx = tid; idx < 8192; idx += 256) {
        int nn = idx >> 6, k = idx & 63;
        int node = base + nn;
        Hs[nn * TPAD + k] = (node < n) ? h[node * 64 + k] : 0.0f;
    }
    __syncthreads();
    const int tf = tid & 7;
    const int tn = tid >> 3;
    float acc[4][4] = {};
    for (int k = 0; k < 64; k += 4) {
        float4 w4[4], h4[4];
        #pragma unroll
        for (int ff = 0; ff < 4; ++ff) w4[ff] = *(const float4*)&Wt[(tf * 4 + ff) * TPAD + k];
        #pragma unroll
        for (int nn = 0; nn < 4; ++nn) h4[nn] = *(const float4*)&Hs[(tn * 4 + nn) * TPAD + k];
        #pragma unroll
        for (int nn = 0; nn < 4; ++nn)
            #pragma unroll
            for (int ff = 0; ff < 4; ++ff)
                acc[nn][ff] += h4[nn].x * w4[ff].x + h4[nn].y * w4[ff].y +
                               h4[nn].z * w4[ff].z + h4[nn].w * w4[ff].w;
    }
    #pragma unroll
    for (int nn = 0; nn < 4; ++nn) {
        int node = base + tn * 4 + nn;
        if (node < n) {
            float d = dis[node];
            float4 o = make_float4(d * acc[nn][0], d * acc[nn][1], d * acc[nn][2], d * acc[nn][3]);
            *(float4*)&t[node * 32 + tf * 4] = o;
        }
    }
}

// ---------------- aggregation (gather over CSR, T pre-scaled by dis) ----------------

template <int F, bool RELU>
__global__ void aggregate_kernel(const float* __restrict__ t, const int* __restrict__ col,
                                 const int* __restrict__ rs, const float* __restrict__ dis,
                                 const float* __restrict__ b, float* __restrict__ out, int n) {
    int gid = blockIdx.x * blockDim.x + threadIdx.x;
    int i, f;
    if (F == 64) { i = gid >> 6; f = threadIdx.x & 63; }
    else         { i = gid >> 5; f = threadIdx.x & 31; }
    if (i >= n) return;
    float acc0 = 0.0f, acc1 = 0.0f;
    int e = rs[i];
    const int end = rs[i + 1];
    for (; e + 8 <= end; e += 8) {
        int s0 = col[e],     s1 = col[e + 1], s2 = col[e + 2], s3 = col[e + 3];
        int s4 = col[e + 4], s5 = col[e + 5], s6 = col[e + 6], s7 = col[e + 7];
        float v0 = t[s0 * F + f], v1 = t[s1 * F + f], v2 = t[s2 * F + f], v3 = t[s3 * F + f];
        float v4 = t[s4 * F + f], v5 = t[s5 * F + f], v6 = t[s6 * F + f], v7 = t[s7 * F + f];
        acc0 += v0; acc1 += v1; acc0 += v2; acc1 += v3;
        acc0 += v4; acc1 += v5; acc0 += v6; acc1 += v7;
    }
    for (; e < end; ++e) acc0 += t[col[e] * F + f];
    float r = dis[i] * (acc0 + acc1 + t[i * F + f]) + b[f];
    if (RELU) r = fmaxf(r, 0.0f);
    out[i * F + f] = r;
}

// ---------------- readout ----------------

__device__ __forceinline__ unsigned mapf(float v) {
    unsigned u = __float_as_uint(v);
    return u ^ ((u & 0x80000000u) ? 0xFFFFFFFFu : 0x80000000u);
}

#define MAPPED_NEG_INF 0x007FFFFFu

__global__ void init_readout_kernel(float* __restrict__ gsum, unsigned* __restrict__ gmax,
                                    int* __restrict__ gcnt) {
    int idx = blockIdx.x * blockDim.x + threadIdx.x;
    if (idx < N_GRAPHS * 32) { gsum[idx] = 0.0f; gmax[idx] = MAPPED_NEG_INF; }
    if (idx < N_GRAPHS) gcnt[idx] = 0;
}

#define R_CHUNK 512
__global__ void readout_kernel(const float* __restrict__ emb, const int* __restrict__ batch,
                               float* __restrict__ gsum, unsigned* __restrict__ gmax,
                               int* __restrict__ gcnt, int n) {
    __shared__ float ssum[N_GRAPHS * 32];
    __shared__ unsigned smax[N_GRAPHS * 32];
    __shared__ int scnt[N_GRAPHS];
    const int tid = threadIdx.x;
    for (int idx = tid; idx < N_GRAPHS * 32; idx += 256) { ssum[idx] = 0.0f; smax[idx] = MAPPED_NEG_INF; }
    if (tid < N_GRAPHS) scnt[tid] = 0;
    __syncthreads();
    const int lane = tid & 31, grp = tid >> 5;
    const int start = blockIdx.x * R_CHUNK;
    const int end = min(start + R_CHUNK, n);
    for (int i = start + grp; i < end; i += 8) {
        int g = batch[i];
        float v = emb[i * 32 + lane];
        atomicAdd(&ssum[g * 32 + lane], v);
        atomicMax(&smax[g * 32 + lane], mapf(v));
        if (lane == 0) atomicAdd(&scnt[g], 1);
    }
    __syncthreads();
    for (int idx = tid; idx < N_GRAPHS * 32; idx += 256) {
        int g = idx >> 5;
        if (scnt[g] > 0) {
            atomicAdd(&gsum[idx], ssum[idx]);
            atomicMax(&gmax[idx], smax[idx]);
        }
    }
    if (tid < N_GRAPHS && scnt[tid] > 0) atomicAdd(&gcnt[tid], scnt[tid]);
}

__global__ void finalize_kernel(const float* __restrict__ gsum, const unsigned* __restrict__ gmax,
                                const int* __restrict__ gcnt, float* __restrict__ out) {
    int idx = blockIdx.x * blockDim.x + threadIdx.x;
    if (idx >= N_GRAPHS * 32) return;
    int g = idx >> 5, f = idx & 31;
    float c = fmaxf((float)gcnt[g], 1.0f);
    out[g * 64 + f] = gsum[idx] / c;
    unsigned u = gmax[idx];
    unsigned bits = (u & 0x80000000u) ? (u ^ 0x80000000u) : ~u;
    out[g * 64 + 32 + f] = __uint_as_float(bits);
}

// ---------------- launch ----------------

extern "C" void kernel_launch(void* const* d_in, const int* in_sizes, int n_in,
                              void* d_out, int out_size, void* d_ws, size_t ws_size,
                              hipStream_t stream) {
    const float* x  = (const float*)d_in[0];
    const float* W1 = (const float*)d_in[1];
    const float* b1 = (const float*)d_in[2];
    const float* W2 = (const float*)d_in[3];
    const float* b2 = (const float*)d_in[4];
    const float* W3 = (const float*)d_in[5];
    const float* b3 = (const float*)d_in[6];
    const int* edge_index = (const int*)d_in[7];
    const int* batch = (const int*)d_in[8];
    float* out = (float*)d_out;

    const int N = in_sizes[0] / 4;
    const int E = in_sizes[7] / 2;
    const int* src = edge_index;
    const int* dst = edge_index + E;
    const int nbuck = (N + 255) >> 8;    // <= 512

    // workspace carve-up (256B aligned)
    char* p = (char*)d_ws;
    auto alloc = [&](size_t bytes) { void* r = (void*)p; p += (bytes + 255) & ~(size_t)255; return r; };
    int*      rs   = (int*)alloc((size_t)(N + 1) * 4);
    float*    dis  = (float*)alloc((size_t)N * 4);
    int*      col  = (int*)alloc((size_t)E * 4);
    float*    T    = (float*)alloc((size_t)N * 64 * 4);
    float*    H    = (float*)alloc((size_t)N * 64 * 4);
    int*      bcnt = (int*)alloc((size_t)512 * 4);
    int*      bbase= (int*)alloc((size_t)513 * 4);
    int*      bcur = (int*)alloc((size_t)512 * 4);
    float*    gsum = (float*)alloc((size_t)N_GRAPHS * 32 * 4);
    unsigned* gmax = (unsigned*)alloc((size_t)N_GRAPHS * 32 * 4);
    int*      gcnt = (int*)alloc((size_t)N_GRAPHS * 4);
    // aliases inside T (consumed before any transform writes T):
    unsigned* binned = (unsigned*)T;          // E ints
    float*    Xs     = T + (size_t)E;         // N*4 floats
    float*    aggX   = T + (size_t)E + (size_t)N * 4;  // N*4 floats
    (void)ws_size; (void)n_in; (void)out_size;

    const int gN = (N + 255) / 256;

    // CSR build
    hipMemsetAsync(bcnt, 0, 512 * 4, stream);
    bucket_hist_kernel<<<(E + EBH - 1) / EBH, 256, 0, stream>>>(dst, bcnt, E, nbuck);
    bucket_scan_kernel<<<1, 512, 0, stream>>>(bcnt, bbase, bcur, nbuck);
    binscatter_kernel<<<(E + EBC - 1) / EBC, 256, 0, stream>>>(src, dst, bcur, binned, E, nbuck);
    build_bucket_kernel<<<nbuck, 256, 0, stream>>>(binned, bbase, x, rs, dis, Xs, col, N);

    // layer 1: aggregate(4) then transform
    agg4_kernel<<<gN, 256, 0, stream>>>(Xs, col, rs, dis, aggX, N);
    transform1b_kernel<<<(N * 64 + 255) / 256, 256, 0, stream>>>(aggX, W1, b1, H, N);
    // layer 2
    transform64_kernel<<<(N + 63) / 64, 256, 0, stream>>>(H, W2, dis, T, N);
    aggregate_kernel<64, true><<<(N * 64 + 255) / 256, 256, 0, stream>>>(T, col, rs, dis, b2, H, N);
    // layer 3
    transform64_32_kernel<<<(N + 127) / 128, 256, 0, stream>>>(H, W3, dis, T, N);
    aggregate_kernel<32, false><<<(N * 32 + 255) / 256, 256, 0, stream>>>(T, col, rs, dis, b3, H, N);

    // readout
    init_readout_kernel<<<(N_GRAPHS * 32 + 255) / 256, 256, 0, stream>>>(gsum, gmax, gcnt);
    readout_kernel<<<(N + R_CHUNK - 1) / R_CHUNK, 256, 0, stream>>>(H, batch, gsum, gmax, gcnt, N);
    finalize_kernel<<<(N_GRAPHS * 32 + 255) / 256, 256, 0, stream>>>(gsum, gmax, gcnt, out);
}

// Round 5
// 378.546 us; speedup vs baseline: 2.3910x; 1.0620x over previous
//
#include <hip/hip_runtime.h>
#include <hip/hip_bf16.h>

#define N_GRAPHS 64
#define TPAD 68     // padded LDS row stride (floats)
#define NT 16       // src tiles (src >> TSHIFT)
#define TSHIFT 13   // 8192 nodes/tile -> 2 MB of T per tile

// ---------------- bucket-level histogram (bucket = dst>>8) ----------------

#define EBH 8192
__global__ void bucket_hist_kernel(const int* __restrict__ dst, int* __restrict__ bcnt,
                                   int E, int nbuck) {
    __shared__ int lh[512];
    const int tid = threadIdx.x;
    for (int i = tid; i < nbuck; i += 256) lh[i] = 0;
    __syncthreads();
    const int e0 = blockIdx.x * EBH;
    const int e1 = min(e0 + EBH, E);
    for (int e = e0 + tid; e < e1; e += 256)
        atomicAdd(&lh[((unsigned)dst[e]) >> 8], 1);
    __syncthreads();
    for (int i = tid; i < nbuck; i += 256) {
        int c = lh[i];
        if (c) atomicAdd(&bcnt[i], c);
    }
}

// exclusive scan of bucket counts (nbuck <= 512), seed bucket cursors
__global__ void bucket_scan_kernel(const int* __restrict__ bcnt, int* __restrict__ bbase,
                                   int* __restrict__ bcur, int nbuck) {
    __shared__ int sh[512];
    const int tid = threadIdx.x;
    int v = (tid < nbuck) ? bcnt[tid] : 0;
    sh[tid] = v;
    __syncthreads();
    for (int off = 1; off < 512; off <<= 1) {
        int t = (tid >= off) ? sh[tid - off] : 0;
        __syncthreads();
        sh[tid] += t;
        __syncthreads();
    }
    if (tid < nbuck) { int e = sh[tid] - v; bbase[tid] = e; bcur[tid] = e; }
    if (tid == nbuck - 1) bbase[nbuck] = sh[tid];
}

// ---------------- binned scatter: packed edge = (dst&255)<<24 | src ----------------

#define EBC 4096
__global__ void binscatter_kernel(const int* __restrict__ src, const int* __restrict__ dst,
                                  int* __restrict__ bcur, unsigned* __restrict__ binned,
                                  int E, int nbuck) {
    __shared__ int lhist[512];
    __shared__ int lbase[512];
    const int tid = threadIdx.x;
    const int e0 = blockIdx.x * EBC;
    const int e1 = min(e0 + EBC, E);
    for (int i = tid; i < nbuck; i += 256) lhist[i] = 0;
    __syncthreads();
    for (int e = e0 + tid; e < e1; e += 256) atomicAdd(&lhist[((unsigned)dst[e]) >> 8], 1);
    __syncthreads();
    for (int i = tid; i < nbuck; i += 256) {
        int c = lhist[i];
        lbase[i] = (c > 0) ? atomicAdd(&bcur[i], c) : 0;
        lhist[i] = 0;
    }
    __syncthreads();
    for (int e = e0 + tid; e < e1; e += 256) {
        int d = dst[e];
        int b = ((unsigned)d) >> 8;
        int off = atomicAdd(&lhist[b], 1);
        binned[lbase[b] + off] = ((unsigned)(d & 255) << 24) | (unsigned)src[e];
    }
}

// ---------------- per-bucket: deg/rs/dis/Xs + (node,srctile)-ordered CSR ----------------

__global__ void build_bucket_kernel(const unsigned* __restrict__ binned, const int* __restrict__ bbase,
                                    const float* __restrict__ x, int* __restrict__ rs,
                                    float* __restrict__ dis_g, float* __restrict__ Xs,
                                    int* __restrict__ col, int n) {
    __shared__ int cnt2[256 * NT];   // per (node-in-bucket, srctile) count -> cursor
    __shared__ int wsum[4];
    const int b = blockIdx.x;
    const int node_base = b << 8;
    const int nb = min(256, n - node_base);
    const int tid = threadIdx.x;
    #pragma unroll
    for (int t = 0; t < NT; ++t) cnt2[tid * NT + t] = 0;
    __syncthreads();
    const int e0 = bbase[b], e1 = bbase[b + 1];
    for (int e = e0 + tid; e < e1; e += 256) {
        unsigned v = binned[e];
        int dloc = v >> 24;
        int t = (int)((v & 0xFFFFFFu) >> TSHIFT);
        atomicAdd(&cnt2[dloc * NT + t], 1);
    }
    __syncthreads();
    // per-node serial scan over tiles -> deg; block scan over node degs
    int deg = 0;
    #pragma unroll
    for (int t = 0; t < NT; ++t) deg += cnt2[tid * NT + t];
    const int lane = tid & 63, wid = tid >> 6;
    int s = deg;
    #pragma unroll
    for (int off = 1; off < 64; off <<= 1) {
        int t = __shfl_up(s, off);
        if (lane >= off) s += t;
    }
    if (lane == 63) wsum[wid] = s;
    __syncthreads();
    int woff = 0;
    for (int w = 0; w < wid; ++w) woff += wsum[w];
    const int excl = woff + s - deg;
    // cnt2 -> absolute cursors
    int run = e0 + excl;
    #pragma unroll
    for (int t = 0; t < NT; ++t) {
        int c = cnt2[tid * NT + t];
        cnt2[tid * NT + t] = run;
        run += c;
    }
    if (tid < nb) {
        int node = node_base + tid;
        rs[node] = e0 + excl;
        float d = rsqrtf((float)deg + 1.0f);
        dis_g[node] = d;
        float4 xv = *(const float4*)&x[node * 4];
        *(float4*)&Xs[node * 4] = make_float4(d * xv.x, d * xv.y, d * xv.z, d * xv.w);
    }
    if (tid == 0 && node_base + nb == n) rs[n] = e1;
    __syncthreads();
    for (int e = e0 + tid; e < e1; e += 256) {
        unsigned v = binned[e];
        int dloc = v >> 24;
        int srcv = (int)(v & 0xFFFFFFu);
        int t = srcv >> TSHIFT;
        int p = atomicAdd(&cnt2[dloc * NT + t], 1);
        col[p] = srcv;
    }
}

// ---------------- layer 1: aggregate x (4-dim) ----------------

__global__ void agg4_kernel(const float* __restrict__ Xs, const int* __restrict__ col,
                            const int* __restrict__ rs, const float* __restrict__ dis,
                            float* __restrict__ aggX, int n) {
    int i = blockIdx.x * blockDim.x + threadIdx.x;
    if (i >= n) return;
    int e = rs[i];
    const int end = rs[i + 1];
    float4 a0 = make_float4(0, 0, 0, 0), a1 = make_float4(0, 0, 0, 0);
    for (; e + 2 <= end; e += 2) {
        int s0 = col[e], s1 = col[e + 1];
        float4 v0 = *(const float4*)&Xs[s0 * 4];
        float4 v1 = *(const float4*)&Xs[s1 * 4];
        a0.x += v0.x; a0.y += v0.y; a0.z += v0.z; a0.w += v0.w;
        a1.x += v1.x; a1.y += v1.y; a1.z += v1.z; a1.w += v1.w;
    }
    if (e < end) {
        float4 v = *(const float4*)&Xs[col[e] * 4];
        a0.x += v.x; a0.y += v.y; a0.z += v.z; a0.w += v.w;
    }
    float4 self = *(const float4*)&Xs[i * 4];
    float d = dis[i];
    float4 r = make_float4(d * (a0.x + a1.x + self.x), d * (a0.y + a1.y + self.y),
                           d * (a0.z + a1.z + self.z), d * (a0.w + a1.w + self.w));
    *(float4*)&aggX[i * 4] = r;
}

// ---------------- fused layer-1 transform + layer-2 pre-transform ----------------
// T[i] = dis[i] * ( relu(aggX[i] @ W1 + b1) @ W2 )

__global__ void fused_l1_kernel(const float* __restrict__ aggX, const float* __restrict__ W1,
                                const float* __restrict__ b1, const float* __restrict__ W2,
                                const float* __restrict__ dis, float* __restrict__ t, int n) {
    __shared__ float W1s[256];
    __shared__ float b1s[64];
    __shared__ float Wt[64 * TPAD];   // Wt[f*TPAD+k] = W2[k][f]
    __shared__ float Hs[64 * TPAD];   // relu'd hidden tile
    const int tid = threadIdx.x;
    const int base = blockIdx.x * 64;
    if (tid < 256) W1s[tid] = W1[tid];
    if (tid < 64) b1s[tid] = b1[tid];
    for (int idx = tid; idx < 4096; idx += 256) {
        int k = idx >> 6, f = idx & 63;
        Wt[f * TPAD + k] = W2[idx];
    }
    __syncthreads();
    for (int idx = tid; idx < 4096; idx += 256) {
        int nn = idx >> 6, k = idx & 63;
        int node = base + nn;
        float v = 0.0f;
        if (node < n) {
            float4 a = *(const float4*)&aggX[node * 4];
            v = fmaxf(a.x * W1s[k] + a.y * W1s[64 + k] + a.z * W1s[128 + k] + a.w * W1s[192 + k]
                      + b1s[k], 0.0f);
        }
        Hs[nn * TPAD + k] = v;
    }
    __syncthreads();
    const int tf = tid & 15;
    const int tn = tid >> 4;
    float acc[4][4] = {};
    for (int k = 0; k < 64; k += 4) {
        float4 w4[4], h4[4];
        #pragma unroll
        for (int ff = 0; ff < 4; ++ff) w4[ff] = *(const float4*)&Wt[(tf * 4 + ff) * TPAD + k];
        #pragma unroll
        for (int nn = 0; nn < 4; ++nn) h4[nn] = *(const float4*)&Hs[(tn * 4 + nn) * TPAD + k];
        #pragma unroll
        for (int nn = 0; nn < 4; ++nn)
            #pragma unroll
            for (int ff = 0; ff < 4; ++ff)
                acc[nn][ff] += h4[nn].x * w4[ff].x + h4[nn].y * w4[ff].y +
                               h4[nn].z * w4[ff].z + h4[nn].w * w4[ff].w;
    }
    #pragma unroll
    for (int nn = 0; nn < 4; ++nn) {
        int node = base + tn * 4 + nn;
        if (node < n) {
            float d = dis[node];
            float4 o = make_float4(d * acc[nn][0], d * acc[nn][1], d * acc[nn][2], d * acc[nn][3]);
            *(float4*)&t[node * 64 + tf * 4] = o;
        }
    }
}

// ---------------- layer-2 aggregate fused with W3 transform ----------------
// r = relu(dis_i*(sum_nbr T + T_self) + b2);  T32[i] = dis_i * (r @ W3)

__global__ void agg64_fused_kernel(const float* __restrict__ t, const int* __restrict__ col,
                                   const int* __restrict__ rs, const float* __restrict__ dis,
                                   const float* __restrict__ b2, const float* __restrict__ W3,
                                   float* __restrict__ t32, int n) {
    __shared__ float W3s[2048];      // W3[f][c], f-major
    __shared__ float rrow[4 * 65];   // relu'd row per wave
    __shared__ float disl[4];
    const int tid = threadIdx.x;
    for (int idx = tid; idx < 2048; idx += 256) W3s[idx] = W3[idx];
    const int w = tid >> 6, f = tid & 63;
    const int i = blockIdx.x * 4 + w;
    if (i < n) {
        float acc0 = 0.0f, acc1 = 0.0f;
        int e = rs[i];
        const int end = rs[i + 1];
        for (; e + 8 <= end; e += 8) {
            int s0 = col[e],     s1 = col[e + 1], s2 = col[e + 2], s3 = col[e + 3];
            int s4 = col[e + 4], s5 = col[e + 5], s6 = col[e + 6], s7 = col[e + 7];
            float v0 = t[s0 * 64 + f], v1 = t[s1 * 64 + f], v2 = t[s2 * 64 + f], v3 = t[s3 * 64 + f];
            float v4 = t[s4 * 64 + f], v5 = t[s5 * 64 + f], v6 = t[s6 * 64 + f], v7 = t[s7 * 64 + f];
            acc0 += v0; acc1 += v1; acc0 += v2; acc1 += v3;
            acc0 += v4; acc1 += v5; acc0 += v6; acc1 += v7;
        }
        for (; e < end; ++e) acc0 += t[col[e] * 64 + f];
        float di = dis[i];
        float r = fmaxf(di * (acc0 + acc1 + t[i * 64 + f]) + b2[f], 0.0f);
        rrow[w * 65 + f] = r;
        if (f == 0) disl[w] = di;
    }
    __syncthreads();
    if (tid < 128) {
        int q = tid >> 5, c = tid & 31;
        int node = blockIdx.x * 4 + q;
        if (node < n) {
            float dot = 0.0f;
            #pragma unroll
            for (int ff = 0; ff < 64; ++ff)
                dot += rrow[q * 65 + ff] * W3s[ff * 32 + c];
            t32[node * 32 + c] = disl[q] * dot;
        }
    }
}

// ---------------- layer-3 aggregate (32-dim) ----------------

__global__ void agg32_kernel(const float* __restrict__ t, const int* __restrict__ col,
                             const int* __restrict__ rs, const float* __restrict__ dis,
                             const float* __restrict__ b, float* __restrict__ out, int n) {
    int gid = blockIdx.x * blockDim.x + threadIdx.x;
    int i = gid >> 5, f = threadIdx.x & 31;
    if (i >= n) return;
    float acc0 = 0.0f, acc1 = 0.0f;
    int e = rs[i];
    const int end = rs[i + 1];
    for (; e + 8 <= end; e += 8) {
        int s0 = col[e],     s1 = col[e + 1], s2 = col[e + 2], s3 = col[e + 3];
        int s4 = col[e + 4], s5 = col[e + 5], s6 = col[e + 6], s7 = col[e + 7];
        float v0 = t[s0 * 32 + f], v1 = t[s1 * 32 + f], v2 = t[s2 * 32 + f], v3 = t[s3 * 32 + f];
        float v4 = t[s4 * 32 + f], v5 = t[s5 * 32 + f], v6 = t[s6 * 32 + f], v7 = t[s7 * 32 + f];
        acc0 += v0; acc1 += v1; acc0 += v2; acc1 += v3;
        acc0 += v4; acc1 += v5; acc0 += v6; acc1 += v7;
    }
    for (; e < end; ++e) acc0 += t[col[e] * 32 + f];
    out[i * 32 + f] = dis[i] * (acc0 + acc1 + t[i * 32 + f]) + b[f];
}

// ---------------- readout ----------------

__device__ __forceinline__ unsigned mapf(float v) {
    unsigned u = __float_as_uint(v);
    return u ^ ((u & 0x80000000u) ? 0xFFFFFFFFu : 0x80000000u);
}

#define MAPPED_NEG_INF 0x007FFFFFu

__global__ void init_readout_kernel(float* __restrict__ gsum, unsigned* __restrict__ gmax,
                                    int* __restrict__ gcnt) {
    int idx = blockIdx.x * blockDim.x + threadIdx.x;
    if (idx < N_GRAPHS * 32) { gsum[idx] = 0.0f; gmax[idx] = MAPPED_NEG_INF; }
    if (idx < N_GRAPHS) gcnt[idx] = 0;
}

#define R_CHUNK 512
__global__ void readout_kernel(const float* __restrict__ emb, const int* __restrict__ batch,
                               float* __restrict__ gsum, unsigned* __restrict__ gmax,
                               int* __restrict__ gcnt, int n) {
    __shared__ float ssum[N_GRAPHS * 32];
    __shared__ unsigned smax[N_GRAPHS * 32];
    __shared__ int scnt[N_GRAPHS];
    const int tid = threadIdx.x;
    for (int idx = tid; idx < N_GRAPHS * 32; idx += 256) { ssum[idx] = 0.0f; smax[idx] = MAPPED_NEG_INF; }
    if (tid < N_GRAPHS) scnt[tid] = 0;
    __syncthreads();
    const int lane = tid & 31, grp = tid >> 5;
    const int start = blockIdx.x * R_CHUNK;
    const int end = min(start + R_CHUNK, n);
    for (int i = start + grp; i < end; i += 8) {
        int g = batch[i];
        float v = emb[i * 32 + lane];
        atomicAdd(&ssum[g * 32 + lane], v);
        atomicMax(&smax[g * 32 + lane], mapf(v));
        if (lane == 0) atomicAdd(&scnt[g], 1);
    }
    __syncthreads();
    for (int idx = tid; idx < N_GRAPHS * 32; idx += 256) {
        int g = idx >> 5;
        if (scnt[g] > 0) {
            atomicAdd(&gsum[idx], ssum[idx]);
            atomicMax(&gmax[idx], smax[idx]);
        }
    }
    if (tid < N_GRAPHS && scnt[tid] > 0) atomicAdd(&gcnt[tid], scnt[tid]);
}

__global__ void finalize_kernel(const float* __restrict__ gsum, const unsigned* __restrict__ gmax,
                                const int* __restrict__ gcnt, float* __restrict__ out) {
    int idx = blockIdx.x * blockDim.x + threadIdx.x;
    if (idx >= N_GRAPHS * 32) return;
    int g = idx >> 5, f = idx & 31;
    float c = fmaxf((float)gcnt[g], 1.0f);
    out[g * 64 + f] = gsum[idx] / c;
    unsigned u = gmax[idx];
    unsigned bits = (u & 0x80000000u) ? (u ^ 0x80000000u) : ~u;
    out[g * 64 + 32 + f] = __uint_as_float(bits);
}

// ---------------- launch ----------------

extern "C" void kernel_launch(void* const* d_in, const int* in_sizes, int n_in,
                              void* d_out, int out_size, void* d_ws, size_t ws_size,
                              hipStream_t stream) {
    const float* x  = (const float*)d_in[0];
    const float* W1 = (const float*)d_in[1];
    const float* b1 = (const float*)d_in[2];
    const float* W2 = (const float*)d_in[3];
    const float* b2 = (const float*)d_in[4];
    const float* W3 = (const float*)d_in[5];
    const float* b3 = (const float*)d_in[6];
    const int* edge_index = (const int*)d_in[7];
    const int* batch = (const int*)d_in[8];
    float* out = (float*)d_out;

    const int N = in_sizes[0] / 4;
    const int E = in_sizes[7] / 2;
    const int* src = edge_index;
    const int* dst = edge_index + E;
    const int nbuck = (N + 255) >> 8;    // <= 512

    // workspace carve-up (256B aligned)
    char* p = (char*)d_ws;
    auto alloc = [&](size_t bytes) { void* r = (void*)p; p += (bytes + 255) & ~(size_t)255; return r; };
    int*      rs   = (int*)alloc((size_t)(N + 1) * 4);
    float*    dis  = (float*)alloc((size_t)N * 4);
    int*      col  = (int*)alloc((size_t)E * 4);
    float*    Xs   = (float*)alloc((size_t)N * 4 * 4);
    float*    aggX = (float*)alloc((size_t)N * 4 * 4);
    float*    T    = (float*)alloc((size_t)N * 64 * 4);   // also: binned (E ints), later H32 (N*32)
    float*    T32  = (float*)alloc((size_t)N * 32 * 4);
    int*      bcnt = (int*)alloc((size_t)512 * 4);
    int*      bbase= (int*)alloc((size_t)513 * 4);
    int*      bcur = (int*)alloc((size_t)512 * 4);
    float*    gsum = (float*)alloc((size_t)N_GRAPHS * 32 * 4);
    unsigned* gmax = (unsigned*)alloc((size_t)N_GRAPHS * 32 * 4);
    int*      gcnt = (int*)alloc((size_t)N_GRAPHS * 4);
    unsigned* binned = (unsigned*)T;   // consumed by build_bucket before fused_l1 writes T
    float*    H32    = T;              // written by agg32 after T is dead
    (void)ws_size; (void)n_in; (void)out_size;

    const int gN = (N + 255) / 256;

    // CSR build (dst-bucket binned, then per-(node,srctile) counting sort)
    hipMemsetAsync(bcnt, 0, 512 * 4, stream);
    bucket_hist_kernel<<<(E + EBH - 1) / EBH, 256, 0, stream>>>(dst, bcnt, E, nbuck);
    bucket_scan_kernel<<<1, 512, 0, stream>>>(bcnt, bbase, bcur, nbuck);
    binscatter_kernel<<<(E + EBC - 1) / EBC, 256, 0, stream>>>(src, dst, bcur, binned, E, nbuck);
    build_bucket_kernel<<<nbuck, 256, 0, stream>>>(binned, bbase, x, rs, dis, Xs, col, N);

    // layer 1 aggregate + fused (W1,relu,b1,W2,dis) transform
    agg4_kernel<<<gN, 256, 0, stream>>>(Xs, col, rs, dis, aggX, N);
    fused_l1_kernel<<<(N + 63) / 64, 256, 0, stream>>>(aggX, W1, b1, W2, dis, T, N);
    // layer 2 aggregate fused with W3 transform
    agg64_fused_kernel<<<(N + 3) / 4, 256, 0, stream>>>(T, col, rs, dis, b2, W3, T32, N);
    // layer 3 aggregate
    agg32_kernel<<<(N * 32 + 255) / 256, 256, 0, stream>>>(T32, col, rs, dis, b3, H32, N);

    // readout
    init_readout_kernel<<<(N_GRAPHS * 32 + 255) / 256, 256, 0, stream>>>(gsum, gmax, gcnt);
    readout_kernel<<<(N + R_CHUNK - 1) / R_CHUNK, 256, 0, stream>>>(H32, batch, gsum, gmax, gcnt, N);
    finalize_kernel<<<(N_GRAPHS * 32 + 255) / 256, 256, 0, stream>>>(gsum, gmax, gcnt, out);
}